// Round 13
// baseline (205.059 us; speedup 1.0000x reference)
//
#include <hip/hip_runtime.h>
#include <hip/hip_bf16.h>
#include <math.h>

#define HH 56
#define WW 56
#define CC 384
#define NHEADS 12
#define HID 1536
#define NR 6272

typedef short bf16x8 __attribute__((ext_vector_type(8)));
typedef float f32x4 __attribute__((ext_vector_type(4)));

__device__ __forceinline__ float gelu_exact(float v) {
    return 0.5f * v * (1.0f + erff(v * 0.70710678118654752f));
}
__device__ __forceinline__ unsigned short f2bf(float f) {
    __hip_bfloat16 h = __float2bfloat16(f);
    unsigned short u; __builtin_memcpy(&u, &h, 2); return u;
}
__device__ __forceinline__ float bf2f(unsigned short u) {
    unsigned int x = ((unsigned int)u) << 16;
    float f; __builtin_memcpy(&f, &x, 4); return f;
}
__device__ __forceinline__ void gload16(unsigned short* lds, const unsigned short* g) {
    __builtin_amdgcn_global_load_lds(
        (const __attribute__((address_space(1))) void*)g,
        (__attribute__((address_space(3))) void*)lds, 16, 0, 0);
}

// ---------------- fused weight convert+transpose for all 4 weights ----------------
__device__ __forceinline__ void wconv_one(const float* W, unsigned short* Wt,
        int K, int N, int id) {
    int n = id % N, kc = id / N;
    unsigned short tmp[8];
    #pragma unroll
    for (int j = 0; j < 8; ++j)
        tmp[j] = f2bf(W[(size_t)(kc * 8 + j) * N + n]);
    *reinterpret_cast<uint4*>(&Wt[(size_t)n * K + kc * 8]) = *reinterpret_cast<uint4*>(tmp);
}
__global__ __launch_bounds__(256) void wconv_all(
        const float* __restrict__ wqkv, const float* __restrict__ wproj,
        const float* __restrict__ w1,   const float* __restrict__ w2,
        unsigned short* __restrict__ qkvT, unsigned short* __restrict__ projT,
        unsigned short* __restrict__ w1T,  unsigned short* __restrict__ w2T) {
    int tid = blockIdx.x * 256 + threadIdx.x;
    if (tid < 55296)            wconv_one(wqkv, qkvT, 384, 1152, tid);
    else if (tid < 73728)       wconv_one(wproj, projT, 384, 384, tid - 55296);
    else if (tid < 147456)      wconv_one(w1, w1T, 384, 1536, tid - 73728);
    else if (tid < 221184)      wconv_one(w2, w2T, 1536, 384, tid - 147456);
}

// ---------------- gemm_ln: LN fused into A-staging; K=384 fixed ----------------
// Block = 128 thr, A-panel 64 rows LN'd into 48KB LDS (XOR-swizzled per 64-elem
// k-tile block), then a BARRIER-FREE K-loop: A frags from LDS, B frags loaded
// straight from global (8KB/k-step -> L1/L2 serviced). 3 N-tiles per block.
// EPI: 0=bias, 1=bias+gelu. Output bf16.
template<int EPI>
__global__ __launch_bounds__(128) void gemm_ln(
        const float* __restrict__ X,
        const float* __restrict__ lng, const float* __restrict__ lnb,
        const unsigned short* __restrict__ Bt,
        const float* __restrict__ bias,
        unsigned short* __restrict__ outh,
        int M, int N) {
    constexpr int K = 384;
    __shared__ unsigned short Al[64 * 384];   // 48KB
    int tid = threadIdx.x;
    int w = tid >> 6, lane = tid & 63;
    int l15 = lane & 15, l4 = lane >> 4;
    int m0 = blockIdx.y * 64;

    // --- LN + stage A: each wave handles 32 rows ---
    int chunk = lane >> 3, off = lane & 7;
    for (int r = w * 32; r < w * 32 + 32; ++r) {
        const float* xr = X + (size_t)(m0 + r) * K;
        float v[6];
        float s = 0.f, s2 = 0.f;
        #pragma unroll
        for (int j = 0; j < 6; ++j) {
            v[j] = xr[lane + j * 64];
            s += v[j]; s2 += v[j] * v[j];
        }
        #pragma unroll
        for (int o = 1; o < 64; o <<= 1) {
            s  += __shfl_xor(s, o, 64);
            s2 += __shfl_xor(s2, o, 64);
        }
        float mu  = s * (1.0f / K);
        float var = s2 * (1.0f / K) - mu * mu;
        float rs  = rsqrtf(var + 1e-5f);
        int slot = (chunk ^ (r & 7)) * 8 + off;
        unsigned short* Ar = &Al[r * 384];
        #pragma unroll
        for (int j = 0; j < 6; ++j) {
            int c = lane + j * 64;
            Ar[j * 64 + slot] = f2bf((v[j] - mu) * rs * lng[c] + lnb[c]);
        }
    }
    __syncthreads();

    // --- 3 N-tiles, barrier-free K-loop ---
    for (int nb = 0; nb < 3; ++nb) {
        int n0 = (blockIdx.x * 3 + nb) * 64;
        f32x4 acc[2][4] = {};
        for (int t = 0; t < 6; ++t) {
            #pragma unroll
            for (int kk = 0; kk < 2; ++kk) {
                bf16x8 af[2], bfr[4];
                #pragma unroll
                for (int i = 0; i < 2; ++i) {
                    int row = w * 32 + i * 16 + l15;
                    int slt = ((kk * 4 + l4) ^ (l15 & 7)) * 8;
                    af[i] = *reinterpret_cast<const bf16x8*>(&Al[row * 384 + t * 64 + slt]);
                }
                #pragma unroll
                for (int j = 0; j < 4; ++j)
                    bfr[j] = *reinterpret_cast<const bf16x8*>(
                        &Bt[(size_t)(n0 + j * 16 + l15) * K + t * 64 + kk * 32 + l4 * 8]);
                #pragma unroll
                for (int i = 0; i < 2; ++i)
                    #pragma unroll
                    for (int j = 0; j < 4; ++j)
                        acc[i][j] = __builtin_amdgcn_mfma_f32_16x16x32_bf16(af[i], bfr[j], acc[i][j], 0, 0, 0);
            }
        }
        #pragma unroll
        for (int i = 0; i < 2; ++i) {
            #pragma unroll
            for (int r = 0; r < 4; ++r) {
                int grow = m0 + w * 32 + i * 16 + l4 * 4 + r;
                #pragma unroll
                for (int j = 0; j < 4; ++j) {
                    int gcol = n0 + j * 16 + l15;
                    float v = acc[i][j][r] + bias[gcol];
                    if (EPI == 1) v = gelu_exact(v);
                    outh[(size_t)grow * N + gcol] = f2bf(v);
                }
            }
        }
    }
}

// ---------------- gemm64 (R10-proven): 64x64 tile, 2 waves, 3-buf counted vmcnt ----------------
template<int EPI, int OUTBF>
__global__ __launch_bounds__(128) void gemm64(
        const unsigned short* __restrict__ A,
        const unsigned short* __restrict__ Bt,
        const float* __restrict__ bias,
        const float* __restrict__ res,
        void* __restrict__ outv,
        int M, int N, int K) {
    __shared__ unsigned short As[3][64 * 64];
    __shared__ unsigned short Bs[3][64 * 64];
    int tid = threadIdx.x;
    int m0 = blockIdx.y * 64, n0 = blockIdx.x * 64;
    int w = tid >> 6, lane = tid & 63;
    int l15 = lane & 15, l4 = lane >> 4;

    int srow = lane >> 3;
    int schunk = (lane & 7) ^ srow;
    const unsigned short* Gb = (w == 0 ? A + (size_t)(m0 + srow) * K
                                       : Bt + (size_t)(n0 + srow) * K) + schunk * 8;
    int ldst = srow * 64 + (lane & 7) * 8;

    auto STAGE = [&](int buf, int t) {
        int k0 = t << 6;
        unsigned short* dst = (w == 0) ? As[buf] : Bs[buf];
        #pragma unroll
        for (int h = 0; h < 8; ++h)
            gload16(&dst[ldst + h * 512], Gb + (size_t)h * 8 * K + k0);
    };

    int c0 = (l4 ^ (l15 & 7)) * 8;
    int ar = (w * 32 + l15) * 64;

    f32x4 acc[2][4] = {};
    int nt = K >> 6;
    STAGE(0, 0);
    STAGE(1, 1);
    asm volatile("s_waitcnt vmcnt(8)" ::: "memory");
    __builtin_amdgcn_s_barrier();
    __builtin_amdgcn_sched_barrier(0);
    for (int t = 0; t < nt; ++t) {
        if (t + 2 < nt) STAGE((t + 2) % 3, t + 2);
        const unsigned short* as = As[t % 3];
        const unsigned short* bs = Bs[t % 3];
        #pragma unroll
        for (int kk = 0; kk < 2; ++kk) {
            int c = c0 ^ (kk * 32);
            bf16x8 af[2], bfr[4];
            #pragma unroll
            for (int i = 0; i < 2; ++i)
                af[i] = *reinterpret_cast<const bf16x8*>(&as[ar + i * 16 * 64 + c]);
            #pragma unroll
            for (int j = 0; j < 4; ++j)
                bfr[j] = *reinterpret_cast<const bf16x8*>(&bs[(j * 16 + l15) * 64 + c]);
            #pragma unroll
            for (int i = 0; i < 2; ++i)
                #pragma unroll
                for (int j = 0; j < 4; ++j)
                    acc[i][j] = __builtin_amdgcn_mfma_f32_16x16x32_bf16(af[i], bfr[j], acc[i][j], 0, 0, 0);
        }
        if (t + 1 < nt) {
            if (t + 2 < nt) asm volatile("s_waitcnt vmcnt(8)" ::: "memory");
            else            asm volatile("s_waitcnt vmcnt(0)" ::: "memory");
            __builtin_amdgcn_s_barrier();
            __builtin_amdgcn_sched_barrier(0);
        }
    }
    float* outf = (float*)outv;
    unsigned short* outh = (unsigned short*)outv;
    #pragma unroll
    for (int i = 0; i < 2; ++i) {
        #pragma unroll
        for (int r = 0; r < 4; ++r) {
            int grow = m0 + w * 32 + i * 16 + l4 * 4 + r;
            #pragma unroll
            for (int j = 0; j < 4; ++j) {
                int gcol = n0 + j * 16 + l15;
                float v = acc[i][j][r] + bias[gcol];
                if (EPI == 1) v = gelu_exact(v);
                if (EPI == 2) v += res[(size_t)grow * N + gcol];
                if (OUTBF) outh[(size_t)grow * N + gcol] = f2bf(v);
                else       outf[(size_t)grow * N + gcol] = v;
            }
        }
    }
}

// ---------------- Tiled neighborhood attention (bf16 qkv in, bf16 out) ----------------
__global__ __launch_bounds__(256) void nattn_tile(const unsigned short* __restrict__ qkvh,
        const float* __restrict__ rpb, unsigned short* __restrict__ outp) {
    __shared__ float Ks[196][36];
    __shared__ float bs[169];
    int tile = blockIdx.x;
    int head = blockIdx.y;
    int bat  = blockIdx.z;
    int tly = tile / 7, tlx = tile % 7;
    int h0 = tly * 8 - 3; h0 = h0 < 0 ? 0 : (h0 > 42 ? 42 : h0);
    int w0 = tlx * 8 - 3; w0 = w0 < 0 ? 0 : (w0 > 42 ? 42 : w0);
    int t = threadIdx.x;
    int posbase = bat * (HH * WW);

    for (int i = t; i < 169; i += 256) bs[i] = rpb[head * 169 + i];
    for (int idx = t; idx < 196 * 4; idx += 256) {
        int row = idx >> 2, seg = idx & 3;
        int iy = h0 + row / 14, ix = w0 + row % 14;
        int gpos = posbase + iy * WW + ix;
        uint4 v = *reinterpret_cast<const uint4*>(&qkvh[(size_t)gpos * 1152 + 384 + head * 32 + seg * 8]);
        unsigned short u[8]; __builtin_memcpy(u, &v, 16);
        #pragma unroll
        for (int j = 0; j < 8; ++j) Ks[row][seg * 8 + j] = bf2f(u[j]);
    }
    __syncthreads();

    int q = t >> 2, c = t & 3;
    int qy = tly * 8 + (q >> 3), qx = tlx * 8 + (q & 7);
    int qpos = posbase + qy * WW + qx;
    const float scale = 0.17677669529663687f;
    float qr[8];
    {
        uint4 v = *reinterpret_cast<const uint4*>(&qkvh[(size_t)qpos * 1152 + head * 32 + c * 8]);
        unsigned short u[8]; __builtin_memcpy(u, &v, 16);
        #pragma unroll
        for (int j = 0; j < 8; ++j) qr[j] = bf2f(u[j]) * scale;
    }
    int sh = qy - 3; sh = sh < 0 ? 0 : (sh > 49 ? 49 : sh);
    int sw = qx - 3; sw = sw < 0 ? 0 : (sw > 49 ? 49 : sw);
    int dy0 = sh - h0, dx0 = sw - w0;
    int bh0 = sh - qy + 6, bw0 = sw - qx + 6;

    float sc[49];
    float mx = -1e30f;
    #pragma unroll
    for (int jh = 0; jh < 7; ++jh) {
        #pragma unroll
        for (int jw = 0; jw < 7; ++jw) {
            int nb = (dy0 + jh) * 14 + dx0 + jw;
            const float* kr = &Ks[nb][c * 8];
            float4 k0 = reinterpret_cast<const float4*>(kr)[0];
            float4 k1 = reinterpret_cast<const float4*>(kr)[1];
            float d = qr[0] * k0.x + qr[1] * k0.y + qr[2] * k0.z + qr[3] * k0.w
                    + qr[4] * k1.x + qr[5] * k1.y + qr[6] * k1.z + qr[7] * k1.w;
            d += __shfl_xor(d, 1, 64);
            d += __shfl_xor(d, 2, 64);
            d += bs[(bh0 + jh) * 13 + bw0 + jw];
            sc[jh * 7 + jw] = d;
            mx = fmaxf(mx, d);
        }
    }
    float se = 0.f;
    #pragma unroll
    for (int j = 0; j < 49; ++j) { sc[j] = __expf(sc[j] - mx); se += sc[j]; }
    float inv = 1.0f / se;

    __syncthreads();
    for (int idx = t; idx < 196 * 4; idx += 256) {
        int row = idx >> 2, seg = idx & 3;
        int iy = h0 + row / 14, ix = w0 + row % 14;
        int gpos = posbase + iy * WW + ix;
        uint4 v = *reinterpret_cast<const uint4*>(&qkvh[(size_t)gpos * 1152 + 768 + head * 32 + seg * 8]);
        unsigned short u[8]; __builtin_memcpy(u, &v, 16);
        #pragma unroll
        for (int j = 0; j < 8; ++j) Ks[row][seg * 8 + j] = bf2f(u[j]);
    }
    __syncthreads();

    float o[8] = {};
    #pragma unroll
    for (int jh = 0; jh < 7; ++jh) {
        #pragma unroll
        for (int jw = 0; jw < 7; ++jw) {
            int nb = (dy0 + jh) * 14 + dx0 + jw;
            float w = sc[jh * 7 + jw] * inv;
            const float* vr = &Ks[nb][c * 8];
            float4 v0 = reinterpret_cast<const float4*>(vr)[0];
            float4 v1 = reinterpret_cast<const float4*>(vr)[1];
            o[0] = fmaf(w, v0.x, o[0]); o[1] = fmaf(w, v0.y, o[1]);
            o[2] = fmaf(w, v0.z, o[2]); o[3] = fmaf(w, v0.w, o[3]);
            o[4] = fmaf(w, v1.x, o[4]); o[5] = fmaf(w, v1.y, o[5]);
            o[6] = fmaf(w, v1.z, o[6]); o[7] = fmaf(w, v1.w, o[7]);
        }
    }
    unsigned short oh[8];
    #pragma unroll
    for (int i = 0; i < 8; ++i) oh[i] = f2bf(o[i]);
    *reinterpret_cast<uint4*>(&outp[(size_t)qpos * CC + head * 32 + c * 8]) =
        *reinterpret_cast<uint4*>(oh);
}

extern "C" void kernel_launch(void* const* d_in, const int* in_sizes, int n_in,
                              void* d_out, int out_size, void* d_ws, size_t ws_size,
                              hipStream_t stream) {
    const float* x     = (const float*)d_in[0];
    const float* ln1g  = (const float*)d_in[1];
    const float* ln1b  = (const float*)d_in[2];
    const float* wqkv  = (const float*)d_in[3];
    const float* bqkv  = (const float*)d_in[4];
    const float* rpb   = (const float*)d_in[5];
    const float* wproj = (const float*)d_in[6];
    const float* bproj = (const float*)d_in[7];
    const float* ln2g  = (const float*)d_in[8];
    const float* ln2b  = (const float*)d_in[9];
    const float* w1    = (const float*)d_in[10];
    const float* b1    = (const float*)d_in[11];
    const float* w2    = (const float*)d_in[12];
    const float* b2    = (const float*)d_in[13];
    float* out = (float*)d_out;

    char* ws = (char*)d_ws;
    unsigned short* qkvh = (unsigned short*)(ws);              // 14.45MB qkv, reused as h1 (19.27MB)
    unsigned short* h1   = (unsigned short*)(ws);
    unsigned short* attn = (unsigned short*)(ws + 19267584);   // 4.8MB
    float*          x2   = (float*)(ws + 24084480);            // 9.6MB
    unsigned short* wqkvT = (unsigned short*)(ws + 33718272);  // 884,736
    unsigned short* wprojT= (unsigned short*)(ws + 34603008);  // 294,912
    unsigned short* w1T   = (unsigned short*)(ws + 34897920);  // 1,179,648
    unsigned short* w2T   = (unsigned short*)(ws + 36077568);  // 1,179,648

    // 1. all weight conversions in one launch
    wconv_all<<<864, 256, 0, stream>>>(wqkv, wproj, w1, w2, wqkvT, wprojT, w1T, w2T);
    // 2. qkv = LN1(x) @ wqkv + b (bf16 out), LN fused
    gemm_ln<0><<<dim3(6, 98), 128, 0, stream>>>(x, ln1g, ln1b, wqkvT, bqkv, qkvh, NR, 1152);
    // 3. neighborhood attention -> attn (bf16)
    nattn_tile<<<dim3(49, NHEADS, 2), 256, 0, stream>>>(qkvh, rpb, attn);
    // 4. x2 = x + attn @ wproj + b (f32 out)
    gemm64<2,0><<<dim3(6, 98), 128, 0, stream>>>(attn, wprojT, bproj, x, x2, NR, 384, 384);
    // 5. h1 = gelu(LN2(x2) @ w1 + b1) (bf16 out), LN fused
    gemm_ln<1><<<dim3(8, 98), 128, 0, stream>>>(x2, ln2g, ln2b, w1T, b1, h1, NR, 1536);
    // 6. out = x2 + h1 @ w2 + b2 (f32 out)
    gemm64<2,0><<<dim3(6, 98), 128, 0, stream>>>(h1, w2T, b2, x2, out, NR, 384, HID);
}

// Round 14
// 114.430 us; speedup vs baseline: 1.7920x; 1.7920x over previous
//
#include <hip/hip_runtime.h>
#include <hip/hip_bf16.h>
#include <math.h>

#define HH 56
#define WW 56
#define CC 384
#define NHEADS 12
#define DHEAD 32
#define HID 1536

typedef short bf16x8 __attribute__((ext_vector_type(8)));
typedef float f32x4 __attribute__((ext_vector_type(4)));

__device__ __forceinline__ float gelu_exact(float v) {
    return 0.5f * v * (1.0f + erff(v * 0.70710678118654752f));
}
__device__ __forceinline__ unsigned short f2bf(float f) {
    __hip_bfloat16 h = __float2bfloat16(f);
    unsigned short u; __builtin_memcpy(&u, &h, 2); return u;
}
__device__ __forceinline__ float bf2f(unsigned short u) {
    unsigned int x = ((unsigned int)u) << 16;
    float f; __builtin_memcpy(&f, &x, 4); return f;
}
__device__ __forceinline__ void gload16(unsigned short* lds, const unsigned short* g) {
    __builtin_amdgcn_global_load_lds(
        (const __attribute__((address_space(1))) void*)g,
        (__attribute__((address_space(3))) void*)lds, 16, 0, 0);
}

// ---------------- fused weight convert+transpose for all 4 weights ----------------
__device__ __forceinline__ void wconv_one(const float* W, unsigned short* Wt,
        int K, int N, int id) {
    int n = id % N, kc = id / N;
    unsigned short tmp[8];
    #pragma unroll
    for (int j = 0; j < 8; ++j)
        tmp[j] = f2bf(W[(size_t)(kc * 8 + j) * N + n]);
    *reinterpret_cast<uint4*>(&Wt[(size_t)n * K + kc * 8]) = *reinterpret_cast<uint4*>(tmp);
}
__global__ __launch_bounds__(256) void wconv_all(
        const float* __restrict__ wqkv, const float* __restrict__ wproj,
        const float* __restrict__ w1,   const float* __restrict__ w2,
        unsigned short* __restrict__ qkvT, unsigned short* __restrict__ projT,
        unsigned short* __restrict__ w1T,  unsigned short* __restrict__ w2T) {
    int tid = blockIdx.x * 256 + threadIdx.x;
    if (tid < 55296)            wconv_one(wqkv, qkvT, 384, 1152, tid);
    else if (tid < 73728)       wconv_one(wproj, projT, 384, 384, tid - 55296);
    else if (tid < 147456)      wconv_one(w1, w1T, 384, 1536, tid - 73728);
    else if (tid < 221184)      wconv_one(w2, w2T, 1536, 384, tid - 147456);
}

// ---------------- LayerNorm: one wave per row of 384, bf16 output ----------------
__global__ __launch_bounds__(256) void ln_bf16(const float* __restrict__ x,
        const float* __restrict__ g, const float* __restrict__ b,
        unsigned short* __restrict__ y, int nrows) {
    int wid = (blockIdx.x * 256 + threadIdx.x) >> 6;
    int lane = threadIdx.x & 63;
    if (wid >= nrows) return;
    const float* xr = x + (size_t)wid * CC;
    float v[6];
    float s = 0.f, s2 = 0.f;
    #pragma unroll
    for (int j = 0; j < 6; ++j) {
        v[j] = xr[lane + j * 64];
        s += v[j]; s2 += v[j] * v[j];
    }
    #pragma unroll
    for (int o = 1; o < 64; o <<= 1) {
        s  += __shfl_xor(s, o, 64);
        s2 += __shfl_xor(s2, o, 64);
    }
    float mu  = s * (1.0f / CC);
    float var = s2 * (1.0f / CC) - mu * mu;
    float rs  = rsqrtf(var + 1e-5f);
    unsigned short* yr = y + (size_t)wid * CC;
    #pragma unroll
    for (int j = 0; j < 6; ++j) {
        int c = lane + j * 64;
        yr[c] = f2bf((v[j] - mu) * rs * g[c] + b[c]);
    }
}

// ---------------- gemm64: 64x64 tile, 2 waves x (32x64), BK=64 ----------------
// 3-buffer LDS pipeline with counted vmcnt (R10-proven) + bijective XCD-chunked
// block swizzle (T1/m204): consecutive dispatched blocks round-robin XCDs, so
// remap the linear tile id into contiguous per-XCD chunks for A-panel L2 reuse.
template<int EPI, int OUTBF>
__global__ __launch_bounds__(128) void gemm64(
        const unsigned short* __restrict__ A,
        const unsigned short* __restrict__ Bt,
        const float* __restrict__ bias,
        const float* __restrict__ res,
        void* __restrict__ outv,
        int M, int N, int K) {
    __shared__ unsigned short As[3][64 * 64];
    __shared__ unsigned short Bs[3][64 * 64];
    int tid = threadIdx.x;

    // T1: bijective XCD swizzle of the linear block id (8 XCDs)
    int gx = gridDim.x;
    int nwg = gx * gridDim.y;
    int lin = blockIdx.y * gx + blockIdx.x;
    int q = nwg >> 3, r = nwg & 7;
    int xcd = lin & 7, idx = lin >> 3;
    int swz = (xcd < r ? xcd * (q + 1) : r * (q + 1) + (xcd - r) * q) + idx;
    int m0 = (swz / gx) * 64, n0 = (swz % gx) * 64;

    int w = tid >> 6, lane = tid & 63;
    int l15 = lane & 15, l4 = lane >> 4;

    // staging: wave0 -> A tile, wave1 -> B tile. 8 rows/group, 8 groups.
    int srow = lane >> 3;                 // 0..7 row within group
    int schunk = (lane & 7) ^ srow;       // inverse-swizzled source chunk
    const unsigned short* Gb = (w == 0 ? A + (size_t)(m0 + srow) * K
                                       : Bt + (size_t)(n0 + srow) * K) + schunk * 8;
    int ldst = srow * 64 + (lane & 7) * 8;  // linear LDS dest (shorts)

    auto STAGE = [&](int buf, int t) {
        int k0 = t << 6;
        unsigned short* dst = (w == 0) ? As[buf] : Bs[buf];
        #pragma unroll
        for (int h = 0; h < 8; ++h)
            gload16(&dst[ldst + h * 512], Gb + (size_t)h * 8 * K + k0);
    };

    int c0 = (l4 ^ (l15 & 7)) * 8;        // read-side swizzled chunk (kk=0)
    int ar = (w * 32 + l15) * 64;         // wave w owns A rows [w*32, w*32+32)

    f32x4 acc[2][4] = {};
    int nt = K >> 6;
    STAGE(0, 0);
    STAGE(1, 1);
    asm volatile("s_waitcnt vmcnt(8)" ::: "memory");   // S(0) landed
    __builtin_amdgcn_s_barrier();
    __builtin_amdgcn_sched_barrier(0);
    for (int t = 0; t < nt; ++t) {
        if (t + 2 < nt) STAGE((t + 2) % 3, t + 2);
        const unsigned short* as = As[t % 3];
        const unsigned short* bs = Bs[t % 3];
        #pragma unroll
        for (int kk = 0; kk < 2; ++kk) {
            int c = c0 ^ (kk * 32);
            bf16x8 af[2], bfr[4];
            #pragma unroll
            for (int i = 0; i < 2; ++i)
                af[i] = *reinterpret_cast<const bf16x8*>(&as[ar + i * 16 * 64 + c]);
            #pragma unroll
            for (int j = 0; j < 4; ++j)
                bfr[j] = *reinterpret_cast<const bf16x8*>(&bs[(j * 16 + l15) * 64 + c]);
            #pragma unroll
            for (int i = 0; i < 2; ++i)
                #pragma unroll
                for (int j = 0; j < 4; ++j)
                    acc[i][j] = __builtin_amdgcn_mfma_f32_16x16x32_bf16(af[i], bfr[j], acc[i][j], 0, 0, 0);
        }
        if (t + 1 < nt) {
            if (t + 2 < nt) asm volatile("s_waitcnt vmcnt(8)" ::: "memory");  // S(t+1) landed
            else            asm volatile("s_waitcnt vmcnt(0)" ::: "memory");  // drain last
            __builtin_amdgcn_s_barrier();
            __builtin_amdgcn_sched_barrier(0);
        }
    }
    float* outf = (float*)outv;
    unsigned short* outh = (unsigned short*)outv;
    #pragma unroll
    for (int i = 0; i < 2; ++i) {
        #pragma unroll
        for (int r2 = 0; r2 < 4; ++r2) {
            int grow = m0 + w * 32 + i * 16 + l4 * 4 + r2;
            #pragma unroll
            for (int j = 0; j < 4; ++j) {
                int gcol = n0 + j * 16 + l15;
                float v = acc[i][j][r2] + bias[gcol];
                if (EPI == 1) v = gelu_exact(v);
                if (EPI == 2) v += res[(size_t)grow * N + gcol];
                if (OUTBF) outh[(size_t)grow * N + gcol] = f2bf(v);
                else       outf[(size_t)grow * N + gcol] = v;
            }
        }
    }
}

// ---------------- Tiled neighborhood attention (bf16 qkv in, bf16 out) ----------------
__global__ __launch_bounds__(256) void nattn_tile(const unsigned short* __restrict__ qkvh,
        const float* __restrict__ rpb, unsigned short* __restrict__ outp) {
    __shared__ float Ks[196][36];
    __shared__ float bs[169];
    int tile = blockIdx.x;
    int head = blockIdx.y;
    int bat  = blockIdx.z;
    int tly = tile / 7, tlx = tile % 7;
    int h0 = tly * 8 - 3; h0 = h0 < 0 ? 0 : (h0 > 42 ? 42 : h0);
    int w0 = tlx * 8 - 3; w0 = w0 < 0 ? 0 : (w0 > 42 ? 42 : w0);
    int t = threadIdx.x;
    int posbase = bat * (HH * WW);

    for (int i = t; i < 169; i += 256) bs[i] = rpb[head * 169 + i];
    for (int idx = t; idx < 196 * 4; idx += 256) {
        int row = idx >> 2, seg = idx & 3;
        int iy = h0 + row / 14, ix = w0 + row % 14;
        int gpos = posbase + iy * WW + ix;
        uint4 v = *reinterpret_cast<const uint4*>(&qkvh[(size_t)gpos * 1152 + 384 + head * 32 + seg * 8]);
        unsigned short u[8]; __builtin_memcpy(u, &v, 16);
        #pragma unroll
        for (int j = 0; j < 8; ++j) Ks[row][seg * 8 + j] = bf2f(u[j]);
    }
    __syncthreads();

    int q = t >> 2, c = t & 3;
    int qy = tly * 8 + (q >> 3), qx = tlx * 8 + (q & 7);
    int qpos = posbase + qy * WW + qx;
    const float scale = 0.17677669529663687f;
    float qr[8];
    {
        uint4 v = *reinterpret_cast<const uint4*>(&qkvh[(size_t)qpos * 1152 + head * 32 + c * 8]);
        unsigned short u[8]; __builtin_memcpy(u, &v, 16);
        #pragma unroll
        for (int j = 0; j < 8; ++j) qr[j] = bf2f(u[j]) * scale;
    }
    int sh = qy - 3; sh = sh < 0 ? 0 : (sh > 49 ? 49 : sh);
    int sw = qx - 3; sw = sw < 0 ? 0 : (sw > 49 ? 49 : sw);
    int dy0 = sh - h0, dx0 = sw - w0;
    int bh0 = sh - qy + 6, bw0 = sw - qx + 6;

    float sc[49];
    float mx = -1e30f;
    #pragma unroll
    for (int jh = 0; jh < 7; ++jh) {
        #pragma unroll
        for (int jw = 0; jw < 7; ++jw) {
            int nb = (dy0 + jh) * 14 + dx0 + jw;
            const float* kr = &Ks[nb][c * 8];
            float4 k0 = reinterpret_cast<const float4*>(kr)[0];
            float4 k1 = reinterpret_cast<const float4*>(kr)[1];
            float d = qr[0] * k0.x + qr[1] * k0.y + qr[2] * k0.z + qr[3] * k0.w
                    + qr[4] * k1.x + qr[5] * k1.y + qr[6] * k1.z + qr[7] * k1.w;
            d += __shfl_xor(d, 1, 64);
            d += __shfl_xor(d, 2, 64);
            d += bs[(bh0 + jh) * 13 + bw0 + jw];
            sc[jh * 7 + jw] = d;
            mx = fmaxf(mx, d);
        }
    }
    float se = 0.f;
    #pragma unroll
    for (int j = 0; j < 49; ++j) { sc[j] = __expf(sc[j] - mx); se += sc[j]; }
    float inv = 1.0f / se;

    __syncthreads();
    for (int idx = t; idx < 196 * 4; idx += 256) {
        int row = idx >> 2, seg = idx & 3;
        int iy = h0 + row / 14, ix = w0 + row % 14;
        int gpos = posbase + iy * WW + ix;
        uint4 v = *reinterpret_cast<const uint4*>(&qkvh[(size_t)gpos * 1152 + 768 + head * 32 + seg * 8]);
        unsigned short u[8]; __builtin_memcpy(u, &v, 16);
        #pragma unroll
        for (int j = 0; j < 8; ++j) Ks[row][seg * 8 + j] = bf2f(u[j]);
    }
    __syncthreads();

    float o[8] = {};
    #pragma unroll
    for (int jh = 0; jh < 7; ++jh) {
        #pragma unroll
        for (int jw = 0; jw < 7; ++jw) {
            int nb = (dy0 + jh) * 14 + dx0 + jw;
            float w = sc[jh * 7 + jw] * inv;
            const float* vr = &Ks[nb][c * 8];
            float4 v0 = reinterpret_cast<const float4*>(vr)[0];
            float4 v1 = reinterpret_cast<const float4*>(vr)[1];
            o[0] = fmaf(w, v0.x, o[0]); o[1] = fmaf(w, v0.y, o[1]);
            o[2] = fmaf(w, v0.z, o[2]); o[3] = fmaf(w, v0.w, o[3]);
            o[4] = fmaf(w, v1.x, o[4]); o[5] = fmaf(w, v1.y, o[5]);
            o[6] = fmaf(w, v1.z, o[6]); o[7] = fmaf(w, v1.w, o[7]);
        }
    }
    unsigned short oh[8];
    #pragma unroll
    for (int i = 0; i < 8; ++i) oh[i] = f2bf(o[i]);
    *reinterpret_cast<uint4*>(&outp[(size_t)qpos * CC + head * 32 + c * 8]) =
        *reinterpret_cast<uint4*>(oh);
}

extern "C" void kernel_launch(void* const* d_in, const int* in_sizes, int n_in,
                              void* d_out, int out_size, void* d_ws, size_t ws_size,
                              hipStream_t stream) {
    const float* x     = (const float*)d_in[0];
    const float* ln1g  = (const float*)d_in[1];
    const float* ln1b  = (const float*)d_in[2];
    const float* wqkv  = (const float*)d_in[3];
    const float* bqkv  = (const float*)d_in[4];
    const float* rpb   = (const float*)d_in[5];
    const float* wproj = (const float*)d_in[6];
    const float* bproj = (const float*)d_in[7];
    const float* ln2g  = (const float*)d_in[8];
    const float* ln2b  = (const float*)d_in[9];
    const float* w1    = (const float*)d_in[10];
    const float* b1    = (const float*)d_in[11];
    const float* w2    = (const float*)d_in[12];
    const float* b2    = (const float*)d_in[13];
    float* out = (float*)d_out;

    const int Nrows = 2 * HH * WW; // 6272
    char* ws = (char*)d_ws;
    unsigned short* qkvh = (unsigned short*)(ws);              // 14.45MB, reused as h1 (19.27MB)
    unsigned short* h1   = (unsigned short*)(ws);
    unsigned short* y1   = (unsigned short*)(ws + 19267584);   // 4,816,896 (also attn_out, y2)
    float*          x2   = (float*)(ws + 24084480);            // 9,633,792
    unsigned short* wqkvT = (unsigned short*)(ws + 33718272);  // 884,736
    unsigned short* wprojT= (unsigned short*)(ws + 34603008);  // 294,912
    unsigned short* w1T   = (unsigned short*)(ws + 34897920);  // 1,179,648
    unsigned short* w2T   = (unsigned short*)(ws + 36077568);  // 1,179,648

    // 0. all weight conversions in one launch
    wconv_all<<<864, 256, 0, stream>>>(wqkv, wproj, w1, w2, wqkvT, wprojT, w1T, w2T);

    // 1. LN1 -> y1 (bf16)
    ln_bf16<<<Nrows / 4, 256, 0, stream>>>(x, ln1g, ln1b, y1, Nrows);
    // 2. qkv = y1 @ w_qkv + b_qkv (bf16 out)
    gemm64<0,1><<<dim3(1152/64, Nrows/64), 128, 0, stream>>>(y1, wqkvT, bqkv, nullptr, qkvh, Nrows, 1152, 384);
    // 3. neighborhood attention -> attn_out (bf16, reuse y1)
    unsigned short* attn_out = y1;
    nattn_tile<<<dim3(49, NHEADS, 2), 256, 0, stream>>>(qkvh, rpb, attn_out);
    // 4. x2 = x + attn_out @ w_proj + b_proj (f32 out)
    gemm64<2,0><<<dim3(384/64, Nrows/64), 128, 0, stream>>>(attn_out, wprojT, bproj, x, x2, Nrows, 384, 384);
    // 5. LN2 -> y2 (bf16, reuse y1)
    unsigned short* y2 = y1;
    ln_bf16<<<Nrows / 4, 256, 0, stream>>>(x2, ln2g, ln2b, y2, Nrows);
    // 6. h1 = gelu(y2 @ w1 + b1) (bf16 out, reuse qkv region)
    gemm64<1,1><<<dim3(HID/64, Nrows/64), 128, 0, stream>>>(y2, w1T, b1, nullptr, h1, Nrows, HID, 384);
    // 7. out = x2 + h1 @ w2 + b2 (f32 out)
    gemm64<2,0><<<dim3(384/64, Nrows/64), 128, 0, stream>>>(h1, w2T, b2, x2, out, Nrows, 384, HID);
}

// Round 15
// 107.722 us; speedup vs baseline: 1.9036x; 1.0623x over previous
//
#include <hip/hip_runtime.h>
#include <hip/hip_bf16.h>
#include <math.h>

#define HH 56
#define WW 56
#define CC 384
#define NHEADS 12
#define DHEAD 32
#define HID 1536

typedef short bf16x8 __attribute__((ext_vector_type(8)));
typedef float f32x4 __attribute__((ext_vector_type(4)));

__device__ __forceinline__ float gelu_exact(float v) {
    return 0.5f * v * (1.0f + erff(v * 0.70710678118654752f));
}
__device__ __forceinline__ unsigned short f2bf(float f) {
    __hip_bfloat16 h = __float2bfloat16(f);
    unsigned short u; __builtin_memcpy(&u, &h, 2); return u;
}
__device__ __forceinline__ float bf2f(unsigned short u) {
    unsigned int x = ((unsigned int)u) << 16;
    float f; __builtin_memcpy(&f, &x, 4); return f;
}
__device__ __forceinline__ void gload16(unsigned short* lds, const unsigned short* g) {
    __builtin_amdgcn_global_load_lds(
        (const __attribute__((address_space(1))) void*)g,
        (__attribute__((address_space(3))) void*)lds, 16, 0, 0);
}

// ---------------- LN row helper: one wave per row of 384, bf16 output ----------------
__device__ __forceinline__ void ln_row(const float* __restrict__ x,
        const float* __restrict__ g, const float* __restrict__ b,
        unsigned short* __restrict__ y, int row) {
    int lane = threadIdx.x & 63;
    const float* xr = x + (size_t)row * CC;
    float v[6];
    float s = 0.f, s2 = 0.f;
    #pragma unroll
    for (int j = 0; j < 6; ++j) {
        v[j] = xr[lane + j * 64];
        s += v[j]; s2 += v[j] * v[j];
    }
    #pragma unroll
    for (int o = 1; o < 64; o <<= 1) {
        s  += __shfl_xor(s, o, 64);
        s2 += __shfl_xor(s2, o, 64);
    }
    float mu  = s * (1.0f / CC);
    float var = s2 * (1.0f / CC) - mu * mu;
    float rs  = rsqrtf(var + 1e-5f);
    unsigned short* yr = y + (size_t)row * CC;
    #pragma unroll
    for (int j = 0; j < 6; ++j) {
        int c = lane + j * 64;
        yr[c] = f2bf((v[j] - mu) * rs * g[c] + b[c]);
    }
}

__global__ __launch_bounds__(256) void ln_bf16(const float* __restrict__ x,
        const float* __restrict__ g, const float* __restrict__ b,
        unsigned short* __restrict__ y, int nrows) {
    int wid = (blockIdx.x * 256 + threadIdx.x) >> 6;
    if (wid < nrows) ln_row(x, g, b, y, wid);
}

// ---------------- prep: LN1 (blocks 0..1567) + all weight transposes (1568..2431) ----------------
__device__ __forceinline__ void wconv_one(const float* W, unsigned short* Wt,
        int K, int N, int id) {
    int n = id % N, kc = id / N;
    unsigned short tmp[8];
    #pragma unroll
    for (int j = 0; j < 8; ++j)
        tmp[j] = f2bf(W[(size_t)(kc * 8 + j) * N + n]);
    *reinterpret_cast<uint4*>(&Wt[(size_t)n * K + kc * 8]) = *reinterpret_cast<uint4*>(tmp);
}
__global__ __launch_bounds__(256) void prep_kernel(
        const float* __restrict__ x, const float* __restrict__ ln1g,
        const float* __restrict__ ln1b, unsigned short* __restrict__ y1,
        const float* __restrict__ wqkv, const float* __restrict__ wproj,
        const float* __restrict__ w1,   const float* __restrict__ w2,
        unsigned short* __restrict__ qkvT, unsigned short* __restrict__ projT,
        unsigned short* __restrict__ w1T,  unsigned short* __restrict__ w2T) {
    int bid = blockIdx.x;
    if (bid < 1568) {
        int row = bid * 4 + (threadIdx.x >> 6);
        if (row < 2 * HH * WW) ln_row(x, ln1g, ln1b, y1, row);
    } else {
        int tid = (bid - 1568) * 256 + threadIdx.x;
        if (tid < 55296)            wconv_one(wqkv, qkvT, 384, 1152, tid);
        else if (tid < 73728)       wconv_one(wproj, projT, 384, 384, tid - 55296);
        else if (tid < 147456)      wconv_one(w1, w1T, 384, 1536, tid - 73728);
        else if (tid < 221184)      wconv_one(w2, w2T, 1536, 384, tid - 147456);
    }
}

// ---------------- gemm64: 64x64 tile, 2 waves x (32x64), BK=64 ----------------
// 3-buffer LDS pipeline with counted vmcnt (R10-proven) + bijective XCD-chunked
// block swizzle (T1/m204, R14-proven +9%).
template<int EPI, int OUTBF>
__global__ __launch_bounds__(128) void gemm64(
        const unsigned short* __restrict__ A,
        const unsigned short* __restrict__ Bt,
        const float* __restrict__ bias,
        const float* __restrict__ res,
        void* __restrict__ outv,
        int M, int N, int K) {
    __shared__ unsigned short As[3][64 * 64];
    __shared__ unsigned short Bs[3][64 * 64];
    int tid = threadIdx.x;

    // T1: bijective XCD swizzle of the linear block id (8 XCDs)
    int gx = gridDim.x;
    int nwg = gx * gridDim.y;
    int lin = blockIdx.y * gx + blockIdx.x;
    int q = nwg >> 3, r = nwg & 7;
    int xcd = lin & 7, idx = lin >> 3;
    int swz = (xcd < r ? xcd * (q + 1) : r * (q + 1) + (xcd - r) * q) + idx;
    int m0 = (swz / gx) * 64, n0 = (swz % gx) * 64;

    int w = tid >> 6, lane = tid & 63;
    int l15 = lane & 15, l4 = lane >> 4;

    int srow = lane >> 3;                 // 0..7 row within group
    int schunk = (lane & 7) ^ srow;       // inverse-swizzled source chunk
    const unsigned short* Gb = (w == 0 ? A + (size_t)(m0 + srow) * K
                                       : Bt + (size_t)(n0 + srow) * K) + schunk * 8;
    int ldst = srow * 64 + (lane & 7) * 8;  // linear LDS dest (shorts)

    auto STAGE = [&](int buf, int t) {
        int k0 = t << 6;
        unsigned short* dst = (w == 0) ? As[buf] : Bs[buf];
        #pragma unroll
        for (int h = 0; h < 8; ++h)
            gload16(&dst[ldst + h * 512], Gb + (size_t)h * 8 * K + k0);
    };

    int c0 = (l4 ^ (l15 & 7)) * 8;        // read-side swizzled chunk (kk=0)
    int ar = (w * 32 + l15) * 64;         // wave w owns A rows [w*32, w*32+32)

    f32x4 acc[2][4] = {};
    int nt = K >> 6;
    STAGE(0, 0);
    STAGE(1, 1);
    asm volatile("s_waitcnt vmcnt(8)" ::: "memory");   // S(0) landed
    __builtin_amdgcn_s_barrier();
    __builtin_amdgcn_sched_barrier(0);
    for (int t = 0; t < nt; ++t) {
        if (t + 2 < nt) STAGE((t + 2) % 3, t + 2);
        const unsigned short* as = As[t % 3];
        const unsigned short* bs = Bs[t % 3];
        #pragma unroll
        for (int kk = 0; kk < 2; ++kk) {
            int c = c0 ^ (kk * 32);
            bf16x8 af[2], bfr[4];
            #pragma unroll
            for (int i = 0; i < 2; ++i)
                af[i] = *reinterpret_cast<const bf16x8*>(&as[ar + i * 16 * 64 + c]);
            #pragma unroll
            for (int j = 0; j < 4; ++j)
                bfr[j] = *reinterpret_cast<const bf16x8*>(&bs[(j * 16 + l15) * 64 + c]);
            #pragma unroll
            for (int i = 0; i < 2; ++i)
                #pragma unroll
                for (int j = 0; j < 4; ++j)
                    acc[i][j] = __builtin_amdgcn_mfma_f32_16x16x32_bf16(af[i], bfr[j], acc[i][j], 0, 0, 0);
        }
        if (t + 1 < nt) {
            if (t + 2 < nt) asm volatile("s_waitcnt vmcnt(8)" ::: "memory");  // S(t+1) landed
            else            asm volatile("s_waitcnt vmcnt(0)" ::: "memory");  // drain last
            __builtin_amdgcn_s_barrier();
            __builtin_amdgcn_sched_barrier(0);
        }
    }
    float* outf = (float*)outv;
    unsigned short* outh = (unsigned short*)outv;
    #pragma unroll
    for (int i = 0; i < 2; ++i) {
        #pragma unroll
        for (int r2 = 0; r2 < 4; ++r2) {
            int grow = m0 + w * 32 + i * 16 + l4 * 4 + r2;
            #pragma unroll
            for (int j = 0; j < 4; ++j) {
                int gcol = n0 + j * 16 + l15;
                float v = acc[i][j][r2] + bias[gcol];
                if (EPI == 1) v = gelu_exact(v);
                if (EPI == 2) v += res[(size_t)grow * N + gcol];
                if (OUTBF) outh[(size_t)grow * N + gcol] = f2bf(v);
                else       outf[(size_t)grow * N + gcol] = v;
            }
        }
    }
}

// ---------------- Tiled neighborhood attention (bf16 qkv in, bf16 out) ----------------
// + T1 XCD swizzle: 1176 blocks = 8x147 exactly; each XCD gets 147 consecutive
// (bat,head,tile) ids -> spatial-halo L2 reuse stays XCD-local.
__global__ __launch_bounds__(256) void nattn_tile(const unsigned short* __restrict__ qkvh,
        const float* __restrict__ rpb, unsigned short* __restrict__ outp) {
    __shared__ float Ks[196][36];
    __shared__ float bs[169];
    int lin = blockIdx.x + 49 * (blockIdx.y + NHEADS * blockIdx.z);
    int xcd = lin & 7, idx = lin >> 3;
    int swz = xcd * 147 + idx;             // nwg=1176, q=147, r=0
    int tile = swz % 49;
    int head = (swz / 49) % NHEADS;
    int bat  = swz / (49 * NHEADS);
    int tly = tile / 7, tlx = tile % 7;
    int h0 = tly * 8 - 3; h0 = h0 < 0 ? 0 : (h0 > 42 ? 42 : h0);
    int w0 = tlx * 8 - 3; w0 = w0 < 0 ? 0 : (w0 > 42 ? 42 : w0);
    int t = threadIdx.x;
    int posbase = bat * (HH * WW);

    for (int i = t; i < 169; i += 256) bs[i] = rpb[head * 169 + i];
    for (int idx2 = t; idx2 < 196 * 4; idx2 += 256) {
        int row = idx2 >> 2, seg = idx2 & 3;
        int iy = h0 + row / 14, ix = w0 + row % 14;
        int gpos = posbase + iy * WW + ix;
        uint4 v = *reinterpret_cast<const uint4*>(&qkvh[(size_t)gpos * 1152 + 384 + head * 32 + seg * 8]);
        unsigned short u[8]; __builtin_memcpy(u, &v, 16);
        #pragma unroll
        for (int j = 0; j < 8; ++j) Ks[row][seg * 8 + j] = bf2f(u[j]);
    }
    __syncthreads();

    int q = t >> 2, c = t & 3;
    int qy = tly * 8 + (q >> 3), qx = tlx * 8 + (q & 7);
    int qpos = posbase + qy * WW + qx;
    const float scale = 0.17677669529663687f;
    float qr[8];
    {
        uint4 v = *reinterpret_cast<const uint4*>(&qkvh[(size_t)qpos * 1152 + head * 32 + c * 8]);
        unsigned short u[8]; __builtin_memcpy(u, &v, 16);
        #pragma unroll
        for (int j = 0; j < 8; ++j) qr[j] = bf2f(u[j]) * scale;
    }
    int sh = qy - 3; sh = sh < 0 ? 0 : (sh > 49 ? 49 : sh);
    int sw = qx - 3; sw = sw < 0 ? 0 : (sw > 49 ? 49 : sw);
    int dy0 = sh - h0, dx0 = sw - w0;
    int bh0 = sh - qy + 6, bw0 = sw - qx + 6;

    float sc[49];
    float mx = -1e30f;
    #pragma unroll
    for (int jh = 0; jh < 7; ++jh) {
        #pragma unroll
        for (int jw = 0; jw < 7; ++jw) {
            int nb = (dy0 + jh) * 14 + dx0 + jw;
            const float* kr = &Ks[nb][c * 8];
            float4 k0 = reinterpret_cast<const float4*>(kr)[0];
            float4 k1 = reinterpret_cast<const float4*>(kr)[1];
            float d = qr[0] * k0.x + qr[1] * k0.y + qr[2] * k0.z + qr[3] * k0.w
                    + qr[4] * k1.x + qr[5] * k1.y + qr[6] * k1.z + qr[7] * k1.w;
            d += __shfl_xor(d, 1, 64);
            d += __shfl_xor(d, 2, 64);
            d += bs[(bh0 + jh) * 13 + bw0 + jw];
            sc[jh * 7 + jw] = d;
            mx = fmaxf(mx, d);
        }
    }
    float se = 0.f;
    #pragma unroll
    for (int j = 0; j < 49; ++j) { sc[j] = __expf(sc[j] - mx); se += sc[j]; }
    float inv = 1.0f / se;

    __syncthreads();
    for (int idx2 = t; idx2 < 196 * 4; idx2 += 256) {
        int row = idx2 >> 2, seg = idx2 & 3;
        int iy = h0 + row / 14, ix = w0 + row % 14;
        int gpos = posbase + iy * WW + ix;
        uint4 v = *reinterpret_cast<const uint4*>(&qkvh[(size_t)gpos * 1152 + 768 + head * 32 + seg * 8]);
        unsigned short u[8]; __builtin_memcpy(u, &v, 16);
        #pragma unroll
        for (int j = 0; j < 8; ++j) Ks[row][seg * 8 + j] = bf2f(u[j]);
    }
    __syncthreads();

    float o[8] = {};
    #pragma unroll
    for (int jh = 0; jh < 7; ++jh) {
        #pragma unroll
        for (int jw = 0; jw < 7; ++jw) {
            int nb = (dy0 + jh) * 14 + dx0 + jw;
            float w = sc[jh * 7 + jw] * inv;
            const float* vr = &Ks[nb][c * 8];
            float4 v0 = reinterpret_cast<const float4*>(vr)[0];
            float4 v1 = reinterpret_cast<const float4*>(vr)[1];
            o[0] = fmaf(w, v0.x, o[0]); o[1] = fmaf(w, v0.y, o[1]);
            o[2] = fmaf(w, v0.z, o[2]); o[3] = fmaf(w, v0.w, o[3]);
            o[4] = fmaf(w, v1.x, o[4]); o[5] = fmaf(w, v1.y, o[5]);
            o[6] = fmaf(w, v1.z, o[6]); o[7] = fmaf(w, v1.w, o[7]);
        }
    }
    unsigned short oh[8];
    #pragma unroll
    for (int i = 0; i < 8; ++i) oh[i] = f2bf(o[i]);
    *reinterpret_cast<uint4*>(&outp[(size_t)qpos * CC + head * 32 + c * 8]) =
        *reinterpret_cast<uint4*>(oh);
}

extern "C" void kernel_launch(void* const* d_in, const int* in_sizes, int n_in,
                              void* d_out, int out_size, void* d_ws, size_t ws_size,
                              hipStream_t stream) {
    const float* x     = (const float*)d_in[0];
    const float* ln1g  = (const float*)d_in[1];
    const float* ln1b  = (const float*)d_in[2];
    const float* wqkv  = (const float*)d_in[3];
    const float* bqkv  = (const float*)d_in[4];
    const float* rpb   = (const float*)d_in[5];
    const float* wproj = (const float*)d_in[6];
    const float* bproj = (const float*)d_in[7];
    const float* ln2g  = (const float*)d_in[8];
    const float* ln2b  = (const float*)d_in[9];
    const float* w1    = (const float*)d_in[10];
    const float* b1    = (const float*)d_in[11];
    const float* w2    = (const float*)d_in[12];
    const float* b2    = (const float*)d_in[13];
    float* out = (float*)d_out;

    const int Nrows = 2 * HH * WW; // 6272
    char* ws = (char*)d_ws;
    unsigned short* qkvh = (unsigned short*)(ws);              // 14.45MB, reused as h1 (19.27MB)
    unsigned short* h1   = (unsigned short*)(ws);
    unsigned short* y1   = (unsigned short*)(ws + 19267584);   // 4,816,896 (also attn_out, y2)
    float*          x2   = (float*)(ws + 24084480);            // 9,633,792
    unsigned short* wqkvT = (unsigned short*)(ws + 33718272);  // 884,736
    unsigned short* wprojT= (unsigned short*)(ws + 34603008);  // 294,912
    unsigned short* w1T   = (unsigned short*)(ws + 34897920);  // 1,179,648
    unsigned short* w2T   = (unsigned short*)(ws + 36077568);  // 1,179,648

    // 0. LN1 + all weight conversions in ONE launch (independent work, partitioned blocks)
    prep_kernel<<<2432, 256, 0, stream>>>(x, ln1g, ln1b, y1,
        wqkv, wproj, w1, w2, wqkvT, wprojT, w1T, w2T);
    // 1. qkv = y1 @ w_qkv + b_qkv (bf16 out)
    gemm64<0,1><<<dim3(1152/64, Nrows/64), 128, 0, stream>>>(y1, wqkvT, bqkv, nullptr, qkvh, Nrows, 1152, 384);
    // 2. neighborhood attention -> attn_out (bf16, reuse y1)
    unsigned short* attn_out = y1;
    nattn_tile<<<dim3(49, NHEADS, 2), 256, 0, stream>>>(qkvh, rpb, attn_out);
    // 3. x2 = x + attn_out @ w_proj + b_proj (f32 out)
    gemm64<2,0><<<dim3(384/64, Nrows/64), 128, 0, stream>>>(attn_out, wprojT, bproj, x, x2, Nrows, 384, 384);
    // 4. LN2 -> y2 (bf16, reuse y1)
    unsigned short* y2 = y1;
    ln_bf16<<<Nrows / 4, 256, 0, stream>>>(x2, ln2g, ln2b, y2, Nrows);
    // 5. h1 = gelu(y2 @ w1 + b1) (bf16 out, reuse qkv region)
    gemm64<1,1><<<dim3(HID/64, Nrows/64), 128, 0, stream>>>(y2, w1T, b1, nullptr, h1, Nrows, HID, 384);
    // 6. out = x2 + h1 @ w2 + b2 (f32 out)
    gemm64<2,0><<<dim3(384/64, Nrows/64), 128, 0, stream>>>(h1, w2T, b2, x2, out, Nrows, 384, HID);
}

// Round 16
// 106.651 us; speedup vs baseline: 1.9227x; 1.0100x over previous
//
#include <hip/hip_runtime.h>
#include <hip/hip_bf16.h>
#include <math.h>

#define HH 56
#define WW 56
#define CC 384
#define NHEADS 12
#define DHEAD 32
#define HID 1536

typedef short bf16x8 __attribute__((ext_vector_type(8)));
typedef float f32x4 __attribute__((ext_vector_type(4)));

__device__ __forceinline__ float gelu_exact(float v) {
    return 0.5f * v * (1.0f + erff(v * 0.70710678118654752f));
}
__device__ __forceinline__ unsigned short f2bf(float f) {
    __hip_bfloat16 h = __float2bfloat16(f);
    unsigned short u; __builtin_memcpy(&u, &h, 2); return u;
}
__device__ __forceinline__ float bf2f(unsigned short u) {
    unsigned int x = ((unsigned int)u) << 16;
    float f; __builtin_memcpy(&f, &x, 4); return f;
}
__device__ __forceinline__ void gload16(unsigned short* lds, const unsigned short* g) {
    __builtin_amdgcn_global_load_lds(
        (const __attribute__((address_space(1))) void*)g,
        (__attribute__((address_space(3))) void*)lds, 16, 0, 0);
}

// ---------------- LN row helper: one wave per row of 384, bf16 output ----------------
__device__ __forceinline__ void ln_row(const float* __restrict__ x,
        const float* __restrict__ g, const float* __restrict__ b,
        unsigned short* __restrict__ y, int row) {
    int lane = threadIdx.x & 63;
    const float* xr = x + (size_t)row * CC;
    float v[6];
    float s = 0.f, s2 = 0.f;
    #pragma unroll
    for (int j = 0; j < 6; ++j) {
        v[j] = xr[lane + j * 64];
        s += v[j]; s2 += v[j] * v[j];
    }
    #pragma unroll
    for (int o = 1; o < 64; o <<= 1) {
        s  += __shfl_xor(s, o, 64);
        s2 += __shfl_xor(s2, o, 64);
    }
    float mu  = s * (1.0f / CC);
    float var = s2 * (1.0f / CC) - mu * mu;
    float rs  = rsqrtf(var + 1e-5f);
    unsigned short* yr = y + (size_t)row * CC;
    #pragma unroll
    for (int j = 0; j < 6; ++j) {
        int c = lane + j * 64;
        yr[c] = f2bf((v[j] - mu) * rs * g[c] + b[c]);
    }
}

__global__ __launch_bounds__(256) void ln_bf16(const float* __restrict__ x,
        const float* __restrict__ g, const float* __restrict__ b,
        unsigned short* __restrict__ y, int nrows) {
    int wid = (blockIdx.x * 256 + threadIdx.x) >> 6;
    if (wid < nrows) ln_row(x, g, b, y, wid);
}

// ---------------- prep: LN1 (blocks 0..1567) + LDS-tiled weight transposes (1568..1999) ----------------
// wtile: coalesced 64x64 f32 read -> LDS (pad 65) -> coalesced bf16 column write.
__device__ __forceinline__ void wtile256(float (*T)[65], const float* __restrict__ W,
        unsigned short* __restrict__ Wt, int K, int N, int tk, int tn) {
    int t = threadIdx.x;
    int r = t >> 2, cs = (t & 3) * 16;
    #pragma unroll
    for (int i = 0; i < 4; ++i) {
        float4 v = *reinterpret_cast<const float4*>(&W[(size_t)(tk * 64 + r) * N + tn * 64 + cs + i * 4]);
        T[r][cs + i * 4 + 0] = v.x; T[r][cs + i * 4 + 1] = v.y;
        T[r][cs + i * 4 + 2] = v.z; T[r][cs + i * 4 + 3] = v.w;
    }
    __syncthreads();
    int n = t >> 2, ks = (t & 3) * 16;
    unsigned short tmp[16];
    #pragma unroll
    for (int j = 0; j < 16; ++j) tmp[j] = f2bf(T[ks + j][n]);
    unsigned short* dst = &Wt[(size_t)(tn * 64 + n) * K + tk * 64 + ks];
    reinterpret_cast<uint4*>(dst)[0] = *reinterpret_cast<uint4*>(tmp);
    reinterpret_cast<uint4*>(dst)[1] = *reinterpret_cast<uint4*>(tmp + 8);
}

__global__ __launch_bounds__(256) void prep_kernel(
        const float* __restrict__ x, const float* __restrict__ ln1g,
        const float* __restrict__ ln1b, unsigned short* __restrict__ y1,
        const float* __restrict__ wqkv, const float* __restrict__ wproj,
        const float* __restrict__ w1,   const float* __restrict__ w2,
        unsigned short* __restrict__ qkvT, unsigned short* __restrict__ projT,
        unsigned short* __restrict__ w1T,  unsigned short* __restrict__ w2T) {
    __shared__ float T[64][65];
    int bid = blockIdx.x;
    if (bid < 1568) {
        int row = bid * 4 + (threadIdx.x >> 6);
        if (row < 2 * HH * WW) ln_row(x, ln1g, ln1b, y1, row);
    } else {
        int id = bid - 1568;   // 0..431
        if (id < 108)          wtile256(T, wqkv, qkvT, 384, 1152, id / 18, id % 18);
        else if (id < 144) { int i2 = id - 108; wtile256(T, wproj, projT, 384, 384,  i2 / 6,  i2 % 6); }
        else if (id < 288) { int i2 = id - 144; wtile256(T, w1,    w1T,   384, 1536, i2 / 24, i2 % 24); }
        else               { int i2 = id - 288; wtile256(T, w2,    w2T,   1536, 384, i2 / 6,  i2 % 6); }
    }
}

// ---------------- gemm64: 64x64 tile, 2 waves x (32x64), BK=64 ----------------
// 3-buffer LDS pipeline with counted vmcnt (R10-proven) + bijective XCD-chunked
// block swizzle (T1/m204, R14-proven +9%).
template<int EPI, int OUTBF>
__global__ __launch_bounds__(128) void gemm64(
        const unsigned short* __restrict__ A,
        const unsigned short* __restrict__ Bt,
        const float* __restrict__ bias,
        const float* __restrict__ res,
        void* __restrict__ outv,
        int M, int N, int K) {
    __shared__ unsigned short As[3][64 * 64];
    __shared__ unsigned short Bs[3][64 * 64];
    int tid = threadIdx.x;

    // T1: bijective XCD swizzle of the linear block id (8 XCDs)
    int gx = gridDim.x;
    int nwg = gx * gridDim.y;
    int lin = blockIdx.y * gx + blockIdx.x;
    int q = nwg >> 3, r = nwg & 7;
    int xcd = lin & 7, idx = lin >> 3;
    int swz = (xcd < r ? xcd * (q + 1) : r * (q + 1) + (xcd - r) * q) + idx;
    int m0 = (swz / gx) * 64, n0 = (swz % gx) * 64;

    int w = tid >> 6, lane = tid & 63;
    int l15 = lane & 15, l4 = lane >> 4;

    int srow = lane >> 3;                 // 0..7 row within group
    int schunk = (lane & 7) ^ srow;       // inverse-swizzled source chunk
    const unsigned short* Gb = (w == 0 ? A + (size_t)(m0 + srow) * K
                                       : Bt + (size_t)(n0 + srow) * K) + schunk * 8;
    int ldst = srow * 64 + (lane & 7) * 8;  // linear LDS dest (shorts)

    auto STAGE = [&](int buf, int t) {
        int k0 = t << 6;
        unsigned short* dst = (w == 0) ? As[buf] : Bs[buf];
        #pragma unroll
        for (int h = 0; h < 8; ++h)
            gload16(&dst[ldst + h * 512], Gb + (size_t)h * 8 * K + k0);
    };

    int c0 = (l4 ^ (l15 & 7)) * 8;        // read-side swizzled chunk (kk=0)
    int ar = (w * 32 + l15) * 64;         // wave w owns A rows [w*32, w*32+32)

    f32x4 acc[2][4] = {};
    int nt = K >> 6;
    STAGE(0, 0);
    STAGE(1, 1);
    asm volatile("s_waitcnt vmcnt(8)" ::: "memory");   // S(0) landed
    __builtin_amdgcn_s_barrier();
    __builtin_amdgcn_sched_barrier(0);
    for (int t = 0; t < nt; ++t) {
        if (t + 2 < nt) STAGE((t + 2) % 3, t + 2);
        const unsigned short* as = As[t % 3];
        const unsigned short* bs = Bs[t % 3];
        #pragma unroll
        for (int kk = 0; kk < 2; ++kk) {
            int c = c0 ^ (kk * 32);
            bf16x8 af[2], bfr[4];
            #pragma unroll
            for (int i = 0; i < 2; ++i)
                af[i] = *reinterpret_cast<const bf16x8*>(&as[ar + i * 16 * 64 + c]);
            #pragma unroll
            for (int j = 0; j < 4; ++j)
                bfr[j] = *reinterpret_cast<const bf16x8*>(&bs[(j * 16 + l15) * 64 + c]);
            #pragma unroll
            for (int i = 0; i < 2; ++i)
                #pragma unroll
                for (int j = 0; j < 4; ++j)
                    acc[i][j] = __builtin_amdgcn_mfma_f32_16x16x32_bf16(af[i], bfr[j], acc[i][j], 0, 0, 0);
        }
        if (t + 1 < nt) {
            if (t + 2 < nt) asm volatile("s_waitcnt vmcnt(8)" ::: "memory");  // S(t+1) landed
            else            asm volatile("s_waitcnt vmcnt(0)" ::: "memory");  // drain last
            __builtin_amdgcn_s_barrier();
            __builtin_amdgcn_sched_barrier(0);
        }
    }
    float* outf = (float*)outv;
    unsigned short* outh = (unsigned short*)outv;
    #pragma unroll
    for (int i = 0; i < 2; ++i) {
        #pragma unroll
        for (int r2 = 0; r2 < 4; ++r2) {
            int grow = m0 + w * 32 + i * 16 + l4 * 4 + r2;
            #pragma unroll
            for (int j = 0; j < 4; ++j) {
                int gcol = n0 + j * 16 + l15;
                float v = acc[i][j][r2] + bias[gcol];
                if (EPI == 1) v = gelu_exact(v);
                if (EPI == 2) v += res[(size_t)grow * N + gcol];
                if (OUTBF) outh[(size_t)grow * N + gcol] = f2bf(v);
                else       outf[(size_t)grow * N + gcol] = v;
            }
        }
    }
}

// ---------------- Tiled neighborhood attention (bf16 qkv in, bf16 out) ----------------
// + T1 XCD swizzle (R15-proven): 1176 blocks = 8x147; each XCD gets 147 consecutive
// (bat,head,tile) ids -> spatial-halo L2 reuse stays XCD-local.
__global__ __launch_bounds__(256) void nattn_tile(const unsigned short* __restrict__ qkvh,
        const float* __restrict__ rpb, unsigned short* __restrict__ outp) {
    __shared__ float Ks[196][36];
    __shared__ float bs[169];
    int lin = blockIdx.x + 49 * (blockIdx.y + NHEADS * blockIdx.z);
    int xcd = lin & 7, idx = lin >> 3;
    int swz = xcd * 147 + idx;             // nwg=1176, q=147, r=0
    int tile = swz % 49;
    int head = (swz / 49) % NHEADS;
    int bat  = swz / (49 * NHEADS);
    int tly = tile / 7, tlx = tile % 7;
    int h0 = tly * 8 - 3; h0 = h0 < 0 ? 0 : (h0 > 42 ? 42 : h0);
    int w0 = tlx * 8 - 3; w0 = w0 < 0 ? 0 : (w0 > 42 ? 42 : w0);
    int t = threadIdx.x;
    int posbase = bat * (HH * WW);

    for (int i = t; i < 169; i += 256) bs[i] = rpb[head * 169 + i];
    for (int idx2 = t; idx2 < 196 * 4; idx2 += 256) {
        int row = idx2 >> 2, seg = idx2 & 3;
        int iy = h0 + row / 14, ix = w0 + row % 14;
        int gpos = posbase + iy * WW + ix;
        uint4 v = *reinterpret_cast<const uint4*>(&qkvh[(size_t)gpos * 1152 + 384 + head * 32 + seg * 8]);
        unsigned short u[8]; __builtin_memcpy(u, &v, 16);
        #pragma unroll
        for (int j = 0; j < 8; ++j) Ks[row][seg * 8 + j] = bf2f(u[j]);
    }
    __syncthreads();

    int q = t >> 2, c = t & 3;
    int qy = tly * 8 + (q >> 3), qx = tlx * 8 + (q & 7);
    int qpos = posbase + qy * WW + qx;
    const float scale = 0.17677669529663687f;
    float qr[8];
    {
        uint4 v = *reinterpret_cast<const uint4*>(&qkvh[(size_t)qpos * 1152 + head * 32 + c * 8]);
        unsigned short u[8]; __builtin_memcpy(u, &v, 16);
        #pragma unroll
        for (int j = 0; j < 8; ++j) qr[j] = bf2f(u[j]) * scale;
    }
    int sh = qy - 3; sh = sh < 0 ? 0 : (sh > 49 ? 49 : sh);
    int sw = qx - 3; sw = sw < 0 ? 0 : (sw > 49 ? 49 : sw);
    int dy0 = sh - h0, dx0 = sw - w0;
    int bh0 = sh - qy + 6, bw0 = sw - qx + 6;

    float sc[49];
    float mx = -1e30f;
    #pragma unroll
    for (int jh = 0; jh < 7; ++jh) {
        #pragma unroll
        for (int jw = 0; jw < 7; ++jw) {
            int nb = (dy0 + jh) * 14 + dx0 + jw;
            const float* kr = &Ks[nb][c * 8];
            float4 k0 = reinterpret_cast<const float4*>(kr)[0];
            float4 k1 = reinterpret_cast<const float4*>(kr)[1];
            float d = qr[0] * k0.x + qr[1] * k0.y + qr[2] * k0.z + qr[3] * k0.w
                    + qr[4] * k1.x + qr[5] * k1.y + qr[6] * k1.z + qr[7] * k1.w;
            d += __shfl_xor(d, 1, 64);
            d += __shfl_xor(d, 2, 64);
            d += bs[(bh0 + jh) * 13 + bw0 + jw];
            sc[jh * 7 + jw] = d;
            mx = fmaxf(mx, d);
        }
    }
    float se = 0.f;
    #pragma unroll
    for (int j = 0; j < 49; ++j) { sc[j] = __expf(sc[j] - mx); se += sc[j]; }
    float inv = 1.0f / se;

    __syncthreads();
    for (int idx2 = t; idx2 < 196 * 4; idx2 += 256) {
        int row = idx2 >> 2, seg = idx2 & 3;
        int iy = h0 + row / 14, ix = w0 + row % 14;
        int gpos = posbase + iy * WW + ix;
        uint4 v = *reinterpret_cast<const uint4*>(&qkvh[(size_t)gpos * 1152 + 768 + head * 32 + seg * 8]);
        unsigned short u[8]; __builtin_memcpy(u, &v, 16);
        #pragma unroll
        for (int j = 0; j < 8; ++j) Ks[row][seg * 8 + j] = bf2f(u[j]);
    }
    __syncthreads();

    float o[8] = {};
    #pragma unroll
    for (int jh = 0; jh < 7; ++jh) {
        #pragma unroll
        for (int jw = 0; jw < 7; ++jw) {
            int nb = (dy0 + jh) * 14 + dx0 + jw;
            float w = sc[jh * 7 + jw] * inv;
            const float* vr = &Ks[nb][c * 8];
            float4 v0 = reinterpret_cast<const float4*>(vr)[0];
            float4 v1 = reinterpret_cast<const float4*>(vr)[1];
            o[0] = fmaf(w, v0.x, o[0]); o[1] = fmaf(w, v0.y, o[1]);
            o[2] = fmaf(w, v0.z, o[2]); o[3] = fmaf(w, v0.w, o[3]);
            o[4] = fmaf(w, v1.x, o[4]); o[5] = fmaf(w, v1.y, o[5]);
            o[6] = fmaf(w, v1.z, o[6]); o[7] = fmaf(w, v1.w, o[7]);
        }
    }
    unsigned short oh[8];
    #pragma unroll
    for (int i = 0; i < 8; ++i) oh[i] = f2bf(o[i]);
    *reinterpret_cast<uint4*>(&outp[(size_t)qpos * CC + head * 32 + c * 8]) =
        *reinterpret_cast<uint4*>(oh);
}

extern "C" void kernel_launch(void* const* d_in, const int* in_sizes, int n_in,
                              void* d_out, int out_size, void* d_ws, size_t ws_size,
                              hipStream_t stream) {
    const float* x     = (const float*)d_in[0];
    const float* ln1g  = (const float*)d_in[1];
    const float* ln1b  = (const float*)d_in[2];
    const float* wqkv  = (const float*)d_in[3];
    const float* bqkv  = (const float*)d_in[4];
    const float* rpb   = (const float*)d_in[5];
    const float* wproj = (const float*)d_in[6];
    const float* bproj = (const float*)d_in[7];
    const float* ln2g  = (const float*)d_in[8];
    const float* ln2b  = (const float*)d_in[9];
    const float* w1    = (const float*)d_in[10];
    const float* b1    = (const float*)d_in[11];
    const float* w2    = (const float*)d_in[12];
    const float* b2    = (const float*)d_in[13];
    float* out = (float*)d_out;

    const int Nrows = 2 * HH * WW; // 6272
    char* ws = (char*)d_ws;
    unsigned short* qkvh = (unsigned short*)(ws);              // 14.45MB, reused as h1 (19.27MB)
    unsigned short* h1   = (unsigned short*)(ws);
    unsigned short* y1   = (unsigned short*)(ws + 19267584);   // 4,816,896 (also attn_out, y2)
    float*          x2   = (float*)(ws + 24084480);            // 9,633,792
    unsigned short* wqkvT = (unsigned short*)(ws + 33718272);  // 884,736
    unsigned short* wprojT= (unsigned short*)(ws + 34603008);  // 294,912
    unsigned short* w1T   = (unsigned short*)(ws + 34897920);  // 1,179,648
    unsigned short* w2T   = (unsigned short*)(ws + 36077568);  // 1,179,648

    // 0. LN1 + all weight transposes (LDS-tiled, coalesced) in ONE launch
    prep_kernel<<<2000, 256, 0, stream>>>(x, ln1g, ln1b, y1,
        wqkv, wproj, w1, w2, wqkvT, wprojT, w1T, w2T);
    // 1. qkv = y1 @ w_qkv + b_qkv (bf16 out)
    gemm64<0,1><<<dim3(1152/64, Nrows/64), 128, 0, stream>>>(y1, wqkvT, bqkv, nullptr, qkvh, Nrows, 1152, 384);
    // 2. neighborhood attention -> attn_out (bf16, reuse y1)
    unsigned short* attn_out = y1;
    nattn_tile<<<dim3(49, NHEADS, 2), 256, 0, stream>>>(qkvh, rpb, attn_out);
    // 3. x2 = x + attn_out @ w_proj + b_proj (f32 out)
    gemm64<2,0><<<dim3(384/64, Nrows/64), 128, 0, stream>>>(attn_out, wprojT, bproj, x, x2, Nrows, 384, 384);
    // 4. LN2 -> y2 (bf16, reuse y1)
    unsigned short* y2 = y1;
    ln_bf16<<<Nrows / 4, 256, 0, stream>>>(x2, ln2g, ln2b, y2, Nrows);
    // 5. h1 = gelu(y2 @ w1 + b1) (bf16 out, reuse qkv region)
    gemm64<1,1><<<dim3(HID/64, Nrows/64), 128, 0, stream>>>(y2, w1T, b1, nullptr, h1, Nrows, HID, 384);
    // 6. out = x2 + h1 @ w2 + b2 (f32 out)
    gemm64<2,0><<<dim3(384/64, Nrows/64), 128, 0, stream>>>(h1, w2T, b2, x2, out, Nrows, 384, HID);
}

// Round 18
// 97.767 us; speedup vs baseline: 2.0974x; 1.0909x over previous
//
#include <hip/hip_runtime.h>
#include <hip/hip_bf16.h>
#include <math.h>

#define HH 56
#define WW 56
#define CC 384
#define NHEADS 12
#define DHEAD 32
#define HID 1536

typedef short bf16x8 __attribute__((ext_vector_type(8)));
typedef float f32x4 __attribute__((ext_vector_type(4)));

__device__ __forceinline__ float gelu_exact(float v) {
    return 0.5f * v * (1.0f + erff(v * 0.70710678118654752f));
}
__device__ __forceinline__ unsigned short f2bf(float f) {
    __hip_bfloat16 h = __float2bfloat16(f);
    unsigned short u; __builtin_memcpy(&u, &h, 2); return u;
}
__device__ __forceinline__ float bf2f(unsigned short u) {
    unsigned int x = ((unsigned int)u) << 16;
    float f; __builtin_memcpy(&f, &x, 4); return f;
}
__device__ __forceinline__ void gload16(unsigned short* lds, const unsigned short* g) {
    __builtin_amdgcn_global_load_lds(
        (const __attribute__((address_space(1))) void*)g,
        (__attribute__((address_space(3))) void*)lds, 16, 0, 0);
}

// ---------------- LN row helper: one wave per row of 384, bf16 output ----------------
__device__ __forceinline__ void ln_row(const float* __restrict__ x,
        const float* __restrict__ g, const float* __restrict__ b,
        unsigned short* __restrict__ y, int row) {
    int lane = threadIdx.x & 63;
    const float* xr = x + (size_t)row * CC;
    float v[6];
    float s = 0.f, s2 = 0.f;
    #pragma unroll
    for (int j = 0; j < 6; ++j) {
        v[j] = xr[lane + j * 64];
        s += v[j]; s2 += v[j] * v[j];
    }
    #pragma unroll
    for (int o = 1; o < 64; o <<= 1) {
        s  += __shfl_xor(s, o, 64);
        s2 += __shfl_xor(s2, o, 64);
    }
    float mu  = s * (1.0f / CC);
    float var = s2 * (1.0f / CC) - mu * mu;
    float rs  = rsqrtf(var + 1e-5f);
    unsigned short* yr = y + (size_t)row * CC;
    #pragma unroll
    for (int j = 0; j < 6; ++j) {
        int c = lane + j * 64;
        yr[c] = f2bf((v[j] - mu) * rs * g[c] + b[c]);
    }
}

__global__ __launch_bounds__(256) void ln_bf16(const float* __restrict__ x,
        const float* __restrict__ g, const float* __restrict__ b,
        unsigned short* __restrict__ y, int nrows) {
    int wid = (blockIdx.x * 256 + threadIdx.x) >> 6;
    if (wid < nrows) ln_row(x, g, b, y, wid);
}

// ---------------- prep: LN1 (blocks 0..1567) + LDS-tiled weight transposes (1568..1999) ----------------
__device__ __forceinline__ void wtile256(float (*T)[65], const float* __restrict__ W,
        unsigned short* __restrict__ Wt, int K, int N, int tk, int tn) {
    int t = threadIdx.x;
    int r = t >> 2, cs = (t & 3) * 16;
    #pragma unroll
    for (int i = 0; i < 4; ++i) {
        float4 v = *reinterpret_cast<const float4*>(&W[(size_t)(tk * 64 + r) * N + tn * 64 + cs + i * 4]);
        T[r][cs + i * 4 + 0] = v.x; T[r][cs + i * 4 + 1] = v.y;
        T[r][cs + i * 4 + 2] = v.z; T[r][cs + i * 4 + 3] = v.w;
    }
    __syncthreads();
    int n = t >> 2, ks = (t & 3) * 16;
    unsigned short tmp[16];
    #pragma unroll
    for (int j = 0; j < 16; ++j) tmp[j] = f2bf(T[ks + j][n]);
    unsigned short* dst = &Wt[(size_t)(tn * 64 + n) * K + tk * 64 + ks];
    reinterpret_cast<uint4*>(dst)[0] = *reinterpret_cast<uint4*>(tmp);
    reinterpret_cast<uint4*>(dst)[1] = *reinterpret_cast<uint4*>(tmp + 8);
}

__global__ __launch_bounds__(256) void prep_kernel(
        const float* __restrict__ x, const float* __restrict__ ln1g,
        const float* __restrict__ ln1b, unsigned short* __restrict__ y1,
        const float* __restrict__ wqkv, const float* __restrict__ wproj,
        const float* __restrict__ w1,   const float* __restrict__ w2,
        unsigned short* __restrict__ qkvT, unsigned short* __restrict__ projT,
        unsigned short* __restrict__ w1T,  unsigned short* __restrict__ w2T) {
    __shared__ float T[64][65];
    int bid = blockIdx.x;
    if (bid < 1568) {
        int row = bid * 4 + (threadIdx.x >> 6);
        if (row < 2 * HH * WW) ln_row(x, ln1g, ln1b, y1, row);
    } else {
        int id = bid - 1568;   // 0..431
        if (id < 108)          wtile256(T, wqkv, qkvT, 384, 1152, id / 18, id % 18);
        else if (id < 144) { int i2 = id - 108; wtile256(T, wproj, projT, 384, 384,  i2 / 6,  i2 % 6); }
        else if (id < 288) { int i2 = id - 144; wtile256(T, w1,    w1T,   384, 1536, i2 / 24, i2 % 24); }
        else               { int i2 = id - 288; wtile256(T, w2,    w2T,   1536, 384, i2 / 6,  i2 % 6); }
    }
}

// ---------------- gemm128: m97 structure — 128x128 tile, 4 waves x (64x64, 4x4 frags) ----------------
// BK=64, single-buffered 32KB LDS (~3 blocks/CU), 2 barriers/K-step, gload_lds
// width 16, both-sides XOR swizzle (R6-proven geometry), XCD bijection (T1).
template<int EPI, int OUTBF>
__global__ __launch_bounds__(256) void gemm128(
        const unsigned short* __restrict__ A,
        const unsigned short* __restrict__ Bt,
        const float* __restrict__ bias,
        const float* __restrict__ res,
        void* __restrict__ outv,
        int M, int N, int K) {
    __shared__ unsigned short As[128 * 64];
    __shared__ unsigned short Bs[128 * 64];
    int tid = threadIdx.x;

    int gx = gridDim.x;
    int nwg = gx * gridDim.y;
    int lin = blockIdx.y * gx + blockIdx.x;
    int q = nwg >> 3, r = nwg & 7;
    int xcd = lin & 7, idx = lin >> 3;
    int swz = (xcd < r ? xcd * (q + 1) : r * (q + 1) + (xcd - r) * q) + idx;
    int m0 = (swz / gx) * 128, n0 = (swz % gx) * 128;

    int w = tid >> 6, lane = tid & 63;
    int wm = w >> 1, wn = w & 1;
    int l15 = lane & 15, l4 = lane >> 4;

    // staging: wave w stages rows [w*32, w*32+32) of both A and B (4 groups of 8)
    int srow = lane >> 3;
    int schunk = (lane & 7) ^ srow;              // inverse swizzle at source
    const unsigned short* Ab = A  + (size_t)(m0 + w * 32 + srow) * K + schunk * 8;
    const unsigned short* Bb = Bt + (size_t)(n0 + w * 32 + srow) * K + schunk * 8;
    int ldst = (w * 32 + srow) * 64 + (lane & 7) * 8;

    int c0 = (l4 ^ (l15 & 7)) * 8;               // read-side swizzled chunk, kk=0
    int ar = (wm * 64 + l15) * 64;
    int br = (wn * 64 + l15) * 64;

    f32x4 acc[4][4] = {};
    int nt = K >> 6;
    for (int t = 0; t < nt; ++t) {
        int k0 = t << 6;
        #pragma unroll
        for (int h = 0; h < 4; ++h) {
            gload16(&As[ldst + h * 512], Ab + (size_t)h * 8 * K + k0);
            gload16(&Bs[ldst + h * 512], Bb + (size_t)h * 8 * K + k0);
        }
        __syncthreads();                          // drains vmcnt (m97 structure)
        #pragma unroll
        for (int kk = 0; kk < 2; ++kk) {
            int c = c0 ^ (kk * 32);
            bf16x8 af[4], bfr[4];
            #pragma unroll
            for (int i = 0; i < 4; ++i)
                af[i] = *reinterpret_cast<const bf16x8*>(&As[ar + i * 16 * 64 + c]);
            #pragma unroll
            for (int j = 0; j < 4; ++j)
                bfr[j] = *reinterpret_cast<const bf16x8*>(&Bs[br + j * 16 * 64 + c]);
            #pragma unroll
            for (int i = 0; i < 4; ++i)
                #pragma unroll
                for (int j = 0; j < 4; ++j)
                    acc[i][j] = __builtin_amdgcn_mfma_f32_16x16x32_bf16(af[i], bfr[j], acc[i][j], 0, 0, 0);
        }
        __syncthreads();
    }
    float* outf = (float*)outv;
    unsigned short* outh = (unsigned short*)outv;
    #pragma unroll
    for (int i = 0; i < 4; ++i) {
        #pragma unroll
        for (int r2 = 0; r2 < 4; ++r2) {
            int grow = m0 + wm * 64 + i * 16 + l4 * 4 + r2;
            #pragma unroll
            for (int j = 0; j < 4; ++j) {
                int gcol = n0 + wn * 64 + j * 16 + l15;
                float v = acc[i][j][r2] + bias[gcol];
                if (EPI == 1) v = gelu_exact(v);
                if (EPI == 2) v += res[(size_t)grow * N + gcol];
                if (OUTBF) outh[(size_t)grow * N + gcol] = f2bf(v);
                else       outf[(size_t)grow * N + gcol] = v;
            }
        }
    }
}

// ---------------- gemm64: 64x64 tile, 2 waves (R10-proven pipeline + T1 swizzle) ----------------
template<int EPI, int OUTBF>
__global__ __launch_bounds__(128) void gemm64(
        const unsigned short* __restrict__ A,
        const unsigned short* __restrict__ Bt,
        const float* __restrict__ bias,
        const float* __restrict__ res,
        void* __restrict__ outv,
        int M, int N, int K) {
    __shared__ unsigned short As[3][64 * 64];
    __shared__ unsigned short Bs[3][64 * 64];
    int tid = threadIdx.x;

    int gx = gridDim.x;
    int nwg = gx * gridDim.y;
    int lin = blockIdx.y * gx + blockIdx.x;
    int q = nwg >> 3, r = nwg & 7;
    int xcd = lin & 7, idx = lin >> 3;
    int swz = (xcd < r ? xcd * (q + 1) : r * (q + 1) + (xcd - r) * q) + idx;
    int m0 = (swz / gx) * 64, n0 = (swz % gx) * 64;

    int w = tid >> 6, lane = tid & 63;
    int l15 = lane & 15, l4 = lane >> 4;

    int srow = lane >> 3;
    int schunk = (lane & 7) ^ srow;
    const unsigned short* Gb = (w == 0 ? A + (size_t)(m0 + srow) * K
                                       : Bt + (size_t)(n0 + srow) * K) + schunk * 8;
    int ldst = srow * 64 + (lane & 7) * 8;

    auto STAGE = [&](int buf, int t) {
        int k0 = t << 6;
        unsigned short* dst = (w == 0) ? As[buf] : Bs[buf];
        #pragma unroll
        for (int h = 0; h < 8; ++h)
            gload16(&dst[ldst + h * 512], Gb + (size_t)h * 8 * K + k0);
    };

    int c0 = (l4 ^ (l15 & 7)) * 8;
    int ar = (w * 32 + l15) * 64;

    f32x4 acc[2][4] = {};
    int nt = K >> 6;
    STAGE(0, 0);
    STAGE(1, 1);
    asm volatile("s_waitcnt vmcnt(8)" ::: "memory");
    __builtin_amdgcn_s_barrier();
    __builtin_amdgcn_sched_barrier(0);
    for (int t = 0; t < nt; ++t) {
        if (t + 2 < nt) STAGE((t + 2) % 3, t + 2);
        const unsigned short* as = As[t % 3];
        const unsigned short* bs = Bs[t % 3];
        #pragma unroll
        for (int kk = 0; kk < 2; ++kk) {
            int c = c0 ^ (kk * 32);
            bf16x8 af[2], bfr[4];
            #pragma unroll
            for (int i = 0; i < 2; ++i)
                af[i] = *reinterpret_cast<const bf16x8*>(&as[ar + i * 16 * 64 + c]);
            #pragma unroll
            for (int j = 0; j < 4; ++j)
                bfr[j] = *reinterpret_cast<const bf16x8*>(&bs[(j * 16 + l15) * 64 + c]);
            #pragma unroll
            for (int i = 0; i < 2; ++i)
                #pragma unroll
                for (int j = 0; j < 4; ++j)
                    acc[i][j] = __builtin_amdgcn_mfma_f32_16x16x32_bf16(af[i], bfr[j], acc[i][j], 0, 0, 0);
        }
        if (t + 1 < nt) {
            if (t + 2 < nt) asm volatile("s_waitcnt vmcnt(8)" ::: "memory");
            else            asm volatile("s_waitcnt vmcnt(0)" ::: "memory");
            __builtin_amdgcn_s_barrier();
            __builtin_amdgcn_sched_barrier(0);
        }
    }
    float* outf = (float*)outv;
    unsigned short* outh = (unsigned short*)outv;
    #pragma unroll
    for (int i = 0; i < 2; ++i) {
        #pragma unroll
        for (int r2 = 0; r2 < 4; ++r2) {
            int grow = m0 + w * 32 + i * 16 + l4 * 4 + r2;
            #pragma unroll
            for (int j = 0; j < 4; ++j) {
                int gcol = n0 + j * 16 + l15;
                float v = acc[i][j][r2] + bias[gcol];
                if (EPI == 1) v = gelu_exact(v);
                if (EPI == 2) v += res[(size_t)grow * N + gcol];
                if (OUTBF) outh[(size_t)grow * N + gcol] = f2bf(v);
                else       outf[(size_t)grow * N + gcol] = v;
            }
        }
    }
}

// ---------------- Tiled neighborhood attention (bf16 qkv in, bf16 out) + T1 swizzle ----------------
__global__ __launch_bounds__(256) void nattn_tile(const unsigned short* __restrict__ qkvh,
        const float* __restrict__ rpb, unsigned short* __restrict__ outp) {
    __shared__ float Ks[196][36];
    __shared__ float bs[169];
    int lin = blockIdx.x + 49 * (blockIdx.y + NHEADS * blockIdx.z);
    int xcd = lin & 7, idx = lin >> 3;
    int swz = xcd * 147 + idx;             // nwg=1176, q=147, r=0
    int tile = swz % 49;
    int head = (swz / 49) % NHEADS;
    int bat  = swz / (49 * NHEADS);
    int tly = tile / 7, tlx = tile % 7;
    int h0 = tly * 8 - 3; h0 = h0 < 0 ? 0 : (h0 > 42 ? 42 : h0);
    int w0 = tlx * 8 - 3; w0 = w0 < 0 ? 0 : (w0 > 42 ? 42 : w0);
    int t = threadIdx.x;
    int posbase = bat * (HH * WW);

    for (int i = t; i < 169; i += 256) bs[i] = rpb[head * 169 + i];
    for (int idx2 = t; idx2 < 196 * 4; idx2 += 256) {
        int row = idx2 >> 2, seg = idx2 & 3;
        int iy = h0 + row / 14, ix = w0 + row % 14;
        int gpos = posbase + iy * WW + ix;
        uint4 v = *reinterpret_cast<const uint4*>(&qkvh[(size_t)gpos * 1152 + 384 + head * 32 + seg * 8]);
        unsigned short u[8]; __builtin_memcpy(u, &v, 16);
        #pragma unroll
        for (int j = 0; j < 8; ++j) Ks[row][seg * 8 + j] = bf2f(u[j]);
    }
    __syncthreads();

    int q = t >> 2, c = t & 3;
    int qy = tly * 8 + (q >> 3), qx = tlx * 8 + (q & 7);
    int qpos = posbase + qy * WW + qx;
    const float scale = 0.17677669529663687f;
    float qr[8];
    {
        uint4 v = *reinterpret_cast<const uint4*>(&qkvh[(size_t)qpos * 1152 + head * 32 + c * 8]);
        unsigned short u[8]; __builtin_memcpy(u, &v, 16);
        #pragma unroll
        for (int j = 0; j < 8; ++j) qr[j] = bf2f(u[j]) * scale;
    }
    int sh = qy - 3; sh = sh < 0 ? 0 : (sh > 49 ? 49 : sh);
    int sw = qx - 3; sw = sw < 0 ? 0 : (sw > 49 ? 49 : sw);
    int dy0 = sh - h0, dx0 = sw - w0;
    int bh0 = sh - qy + 6, bw0 = sw - qx + 6;

    float sc[49];
    float mx = -1e30f;
    #pragma unroll
    for (int jh = 0; jh < 7; ++jh) {
        #pragma unroll
        for (int jw = 0; jw < 7; ++jw) {
            int nb = (dy0 + jh) * 14 + dx0 + jw;
            const float* kr = &Ks[nb][c * 8];
            float4 k0 = reinterpret_cast<const float4*>(kr)[0];
            float4 k1 = reinterpret_cast<const float4*>(kr)[1];
            float d = qr[0] * k0.x + qr[1] * k0.y + qr[2] * k0.z + qr[3] * k0.w
                    + qr[4] * k1.x + qr[5] * k1.y + qr[6] * k1.z + qr[7] * k1.w;
            d += __shfl_xor(d, 1, 64);
            d += __shfl_xor(d, 2, 64);
            d += bs[(bh0 + jh) * 13 + bw0 + jw];
            sc[jh * 7 + jw] = d;
            mx = fmaxf(mx, d);
        }
    }
    float se = 0.f;
    #pragma unroll
    for (int j = 0; j < 49; ++j) { sc[j] = __expf(sc[j] - mx); se += sc[j]; }
    float inv = 1.0f / se;

    __syncthreads();
    for (int idx2 = t; idx2 < 196 * 4; idx2 += 256) {
        int row = idx2 >> 2, seg = idx2 & 3;
        int iy = h0 + row / 14, ix = w0 + row % 14;
        int gpos = posbase + iy * WW + ix;
        uint4 v = *reinterpret_cast<const uint4*>(&qkvh[(size_t)gpos * 1152 + 768 + head * 32 + seg * 8]);
        unsigned short u[8]; __builtin_memcpy(u, &v, 16);
        #pragma unroll
        for (int j = 0; j < 8; ++j) Ks[row][seg * 8 + j] = bf2f(u[j]);
    }
    __syncthreads();

    float o[8] = {};
    #pragma unroll
    for (int jh = 0; jh < 7; ++jh) {
        #pragma unroll
        for (int jw = 0; jw < 7; ++jw) {
            int nb = (dy0 + jh) * 14 + dx0 + jw;
            float w = sc[jh * 7 + jw] * inv;
            const float* vr = &Ks[nb][c * 8];
            float4 v0 = reinterpret_cast<const float4*>(vr)[0];
            float4 v1 = reinterpret_cast<const float4*>(vr)[1];
            o[0] = fmaf(w, v0.x, o[0]); o[1] = fmaf(w, v0.y, o[1]);
            o[2] = fmaf(w, v0.z, o[2]); o[3] = fmaf(w, v0.w, o[3]);
            o[4] = fmaf(w, v1.x, o[4]); o[5] = fmaf(w, v1.y, o[5]);
            o[6] = fmaf(w, v1.z, o[6]); o[7] = fmaf(w, v1.w, o[7]);
        }
    }
    unsigned short oh[8];
    #pragma unroll
    for (int i = 0; i < 8; ++i) oh[i] = f2bf(o[i]);
    *reinterpret_cast<uint4*>(&outp[(size_t)qpos * CC + head * 32 + c * 8]) =
        *reinterpret_cast<uint4*>(oh);
}

extern "C" void kernel_launch(void* const* d_in, const int* in_sizes, int n_in,
                              void* d_out, int out_size, void* d_ws, size_t ws_size,
                              hipStream_t stream) {
    const float* x     = (const float*)d_in[0];
    const float* ln1g  = (const float*)d_in[1];
    const float* ln1b  = (const float*)d_in[2];
    const float* wqkv  = (const float*)d_in[3];
    const float* bqkv  = (const float*)d_in[4];
    const float* rpb   = (const float*)d_in[5];
    const float* wproj = (const float*)d_in[6];
    const float* bproj = (const float*)d_in[7];
    const float* ln2g  = (const float*)d_in[8];
    const float* ln2b  = (const float*)d_in[9];
    const float* w1    = (const float*)d_in[10];
    const float* b1    = (const float*)d_in[11];
    const float* w2    = (const float*)d_in[12];
    const float* b2    = (const float*)d_in[13];
    float* out = (float*)d_out;

    const int Nrows = 2 * HH * WW; // 6272
    char* ws = (char*)d_ws;
    unsigned short* qkvh = (unsigned short*)(ws);              // 14.45MB, reused as h1 (19.27MB)
    unsigned short* h1   = (unsigned short*)(ws);
    unsigned short* y1   = (unsigned short*)(ws + 19267584);   // 4,816,896 (also attn_out, y2)
    float*          x2   = (float*)(ws + 24084480);            // 9,633,792
    unsigned short* wqkvT = (unsigned short*)(ws + 33718272);  // 884,736
    unsigned short* wprojT= (unsigned short*)(ws + 34603008);  // 294,912
    unsigned short* w1T   = (unsigned short*)(ws + 34897920);  // 1,179,648
    unsigned short* w2T   = (unsigned short*)(ws + 36077568);  // 1,179,648

    // 0. LN1 + all weight transposes in ONE launch
    prep_kernel<<<2000, 256, 0, stream>>>(x, ln1g, ln1b, y1,
        wqkv, wproj, w1, w2, wqkvT, wprojT, w1T, w2T);
    // 1. qkv = y1 @ w_qkv + b_qkv (bf16 out) — 128² m97-structure
    gemm128<0,1><<<dim3(1152/128, Nrows/128), 256, 0, stream>>>(y1, wqkvT, bqkv, nullptr, qkvh, Nrows, 1152, 384);
    // 2. neighborhood attention -> attn_out (bf16, reuse y1)
    unsigned short* attn_out = y1;
    nattn_tile<<<dim3(49, NHEADS, 2), 256, 0, stream>>>(qkvh, rpb, attn_out);
    // 3. x2 = x + attn_out @ w_proj + b_proj (f32 out)
    gemm64<2,0><<<dim3(384/64, Nrows/64), 128, 0, stream>>>(attn_out, wprojT, bproj, x, x2, Nrows, 384, 384);
    // 4. LN2 -> y2 (bf16, reuse y1)
    unsigned short* y2 = y1;
    ln_bf16<<<Nrows / 4, 256, 0, stream>>>(x2, ln2g, ln2b, y2, Nrows);
    // 5. h1 = gelu(y2 @ w1 + b1) (bf16 out, reuse qkv region) — 128² m97-structure
    gemm128<1,1><<<dim3(HID/128, Nrows/128), 256, 0, stream>>>(y2, w1T, b1, nullptr, h1, Nrows, HID, 384);
    // 6. out = x2 + h1 @ w2 + b2 (f32 out)
    gemm64<2,0><<<dim3(384/64, Nrows/64), 128, 0, stream>>>(h1, w2T, b2, x2, out, Nrows, 384, HID);
}